// Round 9
// baseline (566.499 us; speedup 1.0000x reference)
//
#include <hip/hip_runtime.h>
#include <cstdint>

#define BN 2
#define HN 16
#define NN 2048
#define DD 64
#define KT 64
#define NT (NN / KT)     // 32 tiles
#define LDP 72           // bf16 LDS row stride (Kb/Vt)
#define LDH 36           // u32 words per row of Pbh (64 bf16 = 32 words + 4 pad)

typedef __attribute__((ext_vector_type(8))) short short8;
typedef __attribute__((ext_vector_type(2))) uint32_t uint2v;
typedef __attribute__((ext_vector_type(4))) uint32_t uint4v;
typedef __attribute__((ext_vector_type(4))) float float4v;

// packed f32->bf16 (RTNE), 2 elems / instr
static __device__ __forceinline__ uint32_t cvt_pk_bf16(float a, float b){
    uint32_t r;
    asm("v_cvt_pk_bf16_f32 %0, %1, %2" : "=v"(r) : "v"(a), "v"(b));
    return r;
}
static __device__ __forceinline__ unsigned short f2bf1(float a){
    return (unsigned short)(cvt_pk_bf16(a, a) & 0xffffu);
}

static __device__ __forceinline__ float4v mfma_bf16(short8 a, short8 b, float4v c){
    return __builtin_amdgcn_mfma_f32_16x16x32_bf16(a, b, c, 0, 0, 0);
}

// Raw barrier: drain LDS ops only; global loads/stores stay in flight.
static __device__ __forceinline__ void barrier_lds(){
    asm volatile("s_waitcnt lgkmcnt(0)" ::: "memory");
    __builtin_amdgcn_s_barrier();
    asm volatile("" ::: "memory");
}

__launch_bounds__(256, 5)
__global__ void attn_fused_kernel(const float* __restrict__ Q,
                                  const float* __restrict__ K,
                                  const float* __restrict__ V,
                                  const float* __restrict__ Bias,
                                  float* __restrict__ Out){
    __shared__ unsigned short Kb[KT][LDP];   // K tile [kv_row][d]
    __shared__ unsigned short Vt[DD][LDP];   // V^T tile [d][kv], kv XOR-swizzled
    __shared__ uint32_t Pbh[4][16][LDH];     // per-wave P bounce (bf16 pairs)

    // XCD-aware decode: each XCD slot owns 2 whole heads; b-pair adjacent.
    const int raw  = blockIdx.x;
    const int slot = raw & 7;
    const int idx  = raw >> 3;
    const int b    = idx & 1;
    const int ghr  = slot * 64 + (idx >> 1);   // (h,rt)
    const int h    = ghr >> 5;
    const int rt   = ghr & 31;

    const int tid = threadIdx.x;
    const int l   = tid & 63;
    const int w   = tid >> 6;
    const int lg  = l >> 4;           // acc-layout row group
    const int ll  = l & 15;           // acc-layout col
    const int vc  = ll * 4;           // vec-layout col

    // coalesced staging coords: wave instr = 4 rows x 256B
    const int srow = tid >> 4;        // 0..15 (+16*i)
    const int scol = (tid & 15) << 2; // element col
    const int vsw  = ((tid >> 1) & 7) << 3;   // Vt write swizzle

    const int qw = rt * 64 + w * 16;
    const size_t bh = (size_t)(b * HN + h);
    const float* Qg = Q + (bh * NN + qw) * DD;
    const float* Kg = K + bh * NN * DD;
    const float* Vg = V + bh * NN * DD;
    // acc-layout bias base: lane (lg,ll) reads row qw+lg*4+r, col sub*16+ll
    const float* BgA = Bias + (size_t)h * NN * NN + (size_t)(qw + lg * 4) * NN + ll;

    // ---- Q fragments (A-frag: row=ll, k=ks*32+lg*8+j) ----
    short8 qf[2];
    {
        const float* qrow = Qg + (size_t)ll * DD + lg * 8;
        #pragma unroll
        for(int ks = 0; ks < 2; ++ks){
            float4v f0 = *(const float4v*)(qrow + ks * 32);
            float4v f1 = *(const float4v*)(qrow + ks * 32 + 4);
            uint4v u;
            u[0] = cvt_pk_bf16(f0[0], f0[1]);
            u[1] = cvt_pk_bf16(f0[2], f0[3]);
            u[2] = cvt_pk_bf16(f1[0], f1[1]);
            u[3] = cvt_pk_bf16(f1[2], f1[3]);
            qf[ks] = __builtin_bit_cast(short8, u);
        }
    }

    float lsum[4];
    #pragma unroll
    for(int r = 0; r < 4; ++r) lsum[r] = 0.f;

    // =============== PASS 1: per-lane partial row sums ===============
    float4v kreg[4];
    #pragma unroll
    for(int i = 0; i < 4; ++i)
        kreg[i] = *(const float4v*)(Kg + (size_t)(srow + 16*i) * DD + scol);

    for(int ct = 0; ct < NT; ++ct){
        barrier_lds();                         // A
        #pragma unroll
        for(int i = 0; i < 4; ++i){            // stage K(t)
            uint2v t = { cvt_pk_bf16(kreg[i][0], kreg[i][1]),
                         cvt_pk_bf16(kreg[i][2], kreg[i][3]) };
            *(uint2v*)&Kb[srow + 16*i][scol] = t;
        }
        // bias(t) -> regs (acc layout, L2-resident); issued before K prefetch
        float bb[16];
        #pragma unroll
        for(int sub = 0; sub < 4; ++sub)
            #pragma unroll
            for(int r = 0; r < 4; ++r)
                bb[sub*4+r] = BgA[(size_t)r * NN + ct*KT + sub*16];
        if(ct + 1 < NT){                       // prefetch K(t+1)
            #pragma unroll
            for(int i = 0; i < 4; ++i)
                kreg[i] = *(const float4v*)(Kg + (size_t)((ct+1)*KT + srow + 16*i) * DD + scol);
        }
        barrier_lds();                         // B

        float4v acc[4];
        #pragma unroll
        for(int sub = 0; sub < 4; ++sub) acc[sub] = (float4v){0.f,0.f,0.f,0.f};
        __builtin_amdgcn_s_setprio(1);
        #pragma unroll
        for(int sub = 0; sub < 4; ++sub){
            short8 b0 = *(const short8*)&Kb[sub*16 + ll][lg*8];
            short8 b1 = *(const short8*)&Kb[sub*16 + ll][32 + lg*8];
            acc[sub] = mfma_bf16(qf[0], b0, acc[sub]);
            acc[sub] = mfma_bf16(qf[1], b1, acc[sub]);
        }
        __builtin_amdgcn_s_setprio(0);

        #pragma unroll
        for(int r = 0; r < 4; ++r){
            float e0 = __expf(acc[0][r] * 0.125f + bb[r]);
            float e1 = __expf(acc[1][r] * 0.125f + bb[4+r]);
            float e2 = __expf(acc[2][r] * 0.125f + bb[8+r]);
            float e3 = __expf(acc[3][r] * 0.125f + bb[12+r]);
            lsum[r] += (e0 + e1) + (e2 + e3);
        }
    }

    float rl[4];
    #pragma unroll
    for(int r = 0; r < 4; ++r){
        #pragma unroll
        for(int d = 1; d < 16; d <<= 1) lsum[r] += __shfl_xor(lsum[r], d);
        rl[r] = 1.0f / lsum[r];
    }

    // =============== PASS 2: attn stores + O = P*V ===============
    float4v oacc[4];
    #pragma unroll
    for(int ds = 0; ds < 4; ++ds) oacc[ds] = (float4v){0.f,0.f,0.f,0.f};

    float* attnW = Out + (size_t)BN*HN*NN*DD
                 + (bh * NN + qw + lg) * (size_t)NN + vc;

    float4v vreg[4];
    #pragma unroll
    for(int i = 0; i < 4; ++i){
        kreg[i] = *(const float4v*)(Kg + (size_t)(srow + 16*i) * DD + scol);
        vreg[i] = *(const float4v*)(Vg + (size_t)(srow + 16*i) * DD + scol);
    }

    for(int ct = 0; ct < NT; ++ct){
        barrier_lds();                         // A
        #pragma unroll
        for(int i = 0; i < 4; ++i){            // stage K(t) + V^T(t) swizzled
            uint2v t = { cvt_pk_bf16(kreg[i][0], kreg[i][1]),
                         cvt_pk_bf16(kreg[i][2], kreg[i][3]) };
            *(uint2v*)&Kb[srow + 16*i][scol] = t;
            #pragma unroll
            for(int j = 0; j < 4; ++j)
                Vt[scol + j][(srow + 16*i) ^ vsw] = f2bf1(vreg[i][j]);
        }
        float bb[16];
        #pragma unroll
        for(int sub = 0; sub < 4; ++sub)
            #pragma unroll
            for(int r = 0; r < 4; ++r)
                bb[sub*4+r] = BgA[(size_t)r * NN + ct*KT + sub*16];
        if(ct + 1 < NT){                       // prefetch K/V(t+1)
            #pragma unroll
            for(int i = 0; i < 4; ++i){
                kreg[i] = *(const float4v*)(Kg + (size_t)((ct+1)*KT + srow + 16*i) * DD + scol);
                vreg[i] = *(const float4v*)(Vg + (size_t)((ct+1)*KT + srow + 16*i) * DD + scol);
            }
        }
        barrier_lds();                         // B

        float4v acc[4];
        #pragma unroll
        for(int sub = 0; sub < 4; ++sub) acc[sub] = (float4v){0.f,0.f,0.f,0.f};
        __builtin_amdgcn_s_setprio(1);
        #pragma unroll
        for(int sub = 0; sub < 4; ++sub){
            short8 b0 = *(const short8*)&Kb[sub*16 + ll][lg*8];
            short8 b1 = *(const short8*)&Kb[sub*16 + ll][32 + lg*8];
            acc[sub] = mfma_bf16(qf[0], b0, acc[sub]);
            acc[sub] = mfma_bf16(qf[1], b1, acc[sub]);
        }
        __builtin_amdgcn_s_setprio(0);

        // p = exp(s)*rl -> bf16 -> Pbh (acc layout, b16 stores)
        #pragma unroll
        for(int sub = 0; sub < 4; ++sub)
            #pragma unroll
            for(int r = 0; r < 4; ++r){
                float p = __expf(acc[sub][r] * 0.125f + bb[sub*4+r]) * rl[r];
                ((unsigned short*)&Pbh[w][lg*4 + r][0])[sub*16 + ll] = f2bf1(p);
            }

        // wave-internal RAW on Pbh
        asm volatile("s_waitcnt lgkmcnt(0)" ::: "memory");

        // PV A-frags: direct bf16 b128 reads (no cvt)
        short8 pf0 = __builtin_bit_cast(short8, *(const uint4v*)&Pbh[w][ll][lg*4]);
        short8 pf1 = __builtin_bit_cast(short8, *(const uint4v*)&Pbh[w][ll][16 + lg*4]);

        // attn store: vec-layout b64 reads -> fp32 -> dwordx4 stores
        #pragma unroll
        for(int it = 0; it < 4; ++it){
            uint2v pw = *(const uint2v*)&Pbh[w][lg + 4*it][ll*2];
            float4v pv;
            pv[0] = __builtin_bit_cast(float, pw[0] << 16);
            pv[1] = __builtin_bit_cast(float, pw[0] & 0xffff0000u);
            pv[2] = __builtin_bit_cast(float, pw[1] << 16);
            pv[3] = __builtin_bit_cast(float, pw[1] & 0xffff0000u);
            *(float4v*)(attnW + (size_t)(it*4) * NN + ct*KT) = pv;
        }

        // PV MFMA: B-frags from swizzled Vt
        __builtin_amdgcn_s_setprio(1);
        #pragma unroll
        for(int ds = 0; ds < 4; ++ds){
            const int rsw = (2*ds + (ll >> 3)) << 3;
            short8 v0 = *(const short8*)&Vt[ds*16 + ll][(lg*8) ^ rsw];
            short8 v1 = *(const short8*)&Vt[ds*16 + ll][(32 + lg*8) ^ rsw];
            oacc[ds] = mfma_bf16(pf0, v0, oacc[ds]);
            oacc[ds] = mfma_bf16(pf1, v1, oacc[ds]);
        }
        __builtin_amdgcn_s_setprio(0);
    }

    // O store
    float* outG = Out + (bh * NN + qw) * (size_t)DD;
    #pragma unroll
    for(int ds = 0; ds < 4; ++ds)
        #pragma unroll
        for(int r = 0; r < 4; ++r)
            outG[(size_t)(lg*4 + r) * DD + ds*16 + ll] = oacc[ds][r];
}

extern "C" void kernel_launch(void* const* d_in, const int* in_sizes, int n_in,
                              void* d_out, int out_size, void* d_ws, size_t ws_size,
                              hipStream_t stream) {
    const float* q    = (const float*)d_in[0];
    const float* k    = (const float*)d_in[1];
    const float* v    = (const float*)d_in[2];
    const float* bias = (const float*)d_in[3];
    float* out = (float*)d_out;

    dim3 grid(BN * HN * (NN / 64));
    dim3 block(256);
    hipLaunchKernelGGL(attn_fused_kernel, grid, block, 0, stream, q, k, v, bias, out);
}

// Round 10
// 485.909 us; speedup vs baseline: 1.1659x; 1.1659x over previous
//
#include <hip/hip_runtime.h>
#include <cstdint>

#define BN 2
#define HN 16
#define NN 2048
#define DD 64
#define KT 64
#define NT (NN / KT)     // 32 tiles
#define LDP 72           // bf16 LDS row stride (Kb/Vt)
#define LDH 36           // u32 words per Pbh row (64 bf16 = 32 words + 4 pad)

typedef __attribute__((ext_vector_type(8))) short short8;
typedef __attribute__((ext_vector_type(2))) uint32_t uint2v;
typedef __attribute__((ext_vector_type(4))) uint32_t uint4v;
typedef __attribute__((ext_vector_type(4))) float float4v;

// packed f32->bf16 (RTNE), 2 elems / instr
static __device__ __forceinline__ uint32_t cvt_pk_bf16(float a, float b){
    uint32_t r;
    asm("v_cvt_pk_bf16_f32 %0, %1, %2" : "=v"(r) : "v"(a), "v"(b));
    return r;
}
static __device__ __forceinline__ unsigned short f2bf1(float a){
    return (unsigned short)(cvt_pk_bf16(a, a) & 0xffffu);
}

static __device__ __forceinline__ short8 pack8(float4v f0, float4v f1){
    uint4v u;
    u[0] = cvt_pk_bf16(f0[0], f0[1]);
    u[1] = cvt_pk_bf16(f0[2], f0[3]);
    u[2] = cvt_pk_bf16(f1[0], f1[1]);
    u[3] = cvt_pk_bf16(f1[2], f1[3]);
    return __builtin_bit_cast(short8, u);
}

static __device__ __forceinline__ float4v mfma_bf16(short8 a, short8 b, float4v c){
    return __builtin_amdgcn_mfma_f32_16x16x32_bf16(a, b, c, 0, 0, 0);
}

// Raw barrier: drain LDS ops only; global loads/stores stay in flight.
static __device__ __forceinline__ void barrier_lds(){
    asm volatile("s_waitcnt lgkmcnt(0)" ::: "memory");
    __builtin_amdgcn_s_barrier();
    asm volatile("" ::: "memory");
}

__launch_bounds__(256, 4)
__global__ void attn_fused_kernel(const float* __restrict__ Q,
                                  const float* __restrict__ K,
                                  const float* __restrict__ V,
                                  const float* __restrict__ Bias,
                                  float* __restrict__ Out){
    __shared__ unsigned short Kb[KT][LDP];   // K tile [kv_row][d]   (pass 2 only)
    __shared__ unsigned short Vt[DD][LDP];   // V^T tile [d][kv], kv XOR-swizzled
    __shared__ uint32_t Pbh[4][16][LDH];     // per-wave P bounce (bf16 pairs)

    // XCD-aware decode: each XCD slot owns 2 whole heads; b-pair adjacent.
    const int raw  = blockIdx.x;
    const int slot = raw & 7;
    const int idx  = raw >> 3;
    const int b    = idx & 1;
    const int ghr  = slot * 64 + (idx >> 1);   // (h,rt)
    const int h    = ghr >> 5;
    const int rt   = ghr & 31;

    const int tid = threadIdx.x;
    const int l   = tid & 63;
    const int w   = tid >> 6;
    const int lg  = l >> 4;           // acc-layout row group
    const int ll  = l & 15;           // acc-layout col
    const int vc  = ll * 4;           // vec-layout col

    // coalesced staging coords (pass 2): wave instr = 4 rows x 256B
    const int srow = tid >> 4;        // 0..15 (+16*i)
    const int scol = (tid & 15) << 2; // element col
    const int vsw  = ((tid >> 1) & 7) << 3;   // Vt write swizzle

    const int qw = rt * 64 + w * 16;
    const size_t bh = (size_t)(b * HN + h);
    const float* Qg = Q + (bh * NN + qw) * DD;
    const float* Kg = K + bh * NN * DD;
    const float* Vg = V + bh * NN * DD;
    // acc-layout bias base: lane (lg,ll) reads row qw+lg*4+r, col sub*16+ll
    const float* BgA = Bias + (size_t)h * NN * NN + (size_t)(qw + lg * 4) * NN + ll;
    // direct K fragment base for pass 1: row = sub*16+ll, cols lg*8..
    const float* KgF = Kg + (size_t)ll * DD + lg * 8;

    // ---- Q fragments (A-frag: row=ll, k=ks*32+lg*8+j) ----
    short8 qf[2];
    {
        const float* qrow = Qg + (size_t)ll * DD + lg * 8;
        #pragma unroll
        for(int ks = 0; ks < 2; ++ks)
            qf[ks] = pack8(*(const float4v*)(qrow + ks * 32),
                           *(const float4v*)(qrow + ks * 32 + 4));
    }

    float lsum[4];
    #pragma unroll
    for(int r = 0; r < 4; ++r) lsum[r] = 0.f;

    // ====== PASS 1: barrier-free, LDS-free. K fragments direct from global ======
    #pragma unroll 1
    for(int ct = 0; ct < NT; ++ct){
        // bias(t) first: in flight while K loads + MFMA run
        float bb[16];
        #pragma unroll
        for(int sub = 0; sub < 4; ++sub)
            #pragma unroll
            for(int r = 0; r < 4; ++r)
                bb[sub*4+r] = BgA[(size_t)r * NN + ct*KT + sub*16];

        float4v acc[4];
        #pragma unroll
        for(int sub = 0; sub < 4; ++sub) acc[sub] = (float4v){0.f,0.f,0.f,0.f};

        #pragma unroll
        for(int sub = 0; sub < 4; ++sub){
            const float* kr = KgF + (size_t)(ct*KT + sub*16) * DD;
            float4v f0 = *(const float4v*)(kr);
            float4v f1 = *(const float4v*)(kr + 4);
            float4v f2 = *(const float4v*)(kr + 32);
            float4v f3 = *(const float4v*)(kr + 36);
            short8 k0 = pack8(f0, f1);
            short8 k1 = pack8(f2, f3);
            acc[sub] = mfma_bf16(qf[0], k0, acc[sub]);
            acc[sub] = mfma_bf16(qf[1], k1, acc[sub]);
        }

        #pragma unroll
        for(int r = 0; r < 4; ++r){
            float e0 = __expf(acc[0][r] * 0.125f + bb[r]);
            float e1 = __expf(acc[1][r] * 0.125f + bb[4+r]);
            float e2 = __expf(acc[2][r] * 0.125f + bb[8+r]);
            float e3 = __expf(acc[3][r] * 0.125f + bb[12+r]);
            lsum[r] += (e0 + e1) + (e2 + e3);
        }
    }

    float rl[4];
    #pragma unroll
    for(int r = 0; r < 4; ++r){
        #pragma unroll
        for(int d = 1; d < 16; d <<= 1) lsum[r] += __shfl_xor(lsum[r], d);
        rl[r] = 1.0f / lsum[r];
    }

    // ====== PASS 2: staged K/V, attn stores + O = P*V ======
    float4v oacc[4];
    #pragma unroll
    for(int ds = 0; ds < 4; ++ds) oacc[ds] = (float4v){0.f,0.f,0.f,0.f};

    float* attnW = Out + (size_t)BN*HN*NN*DD
                 + (bh * NN + qw + lg) * (size_t)NN + vc;

    float4v kreg[4], vreg[4];
    #pragma unroll
    for(int i = 0; i < 4; ++i){
        kreg[i] = *(const float4v*)(Kg + (size_t)(srow + 16*i) * DD + scol);
        vreg[i] = *(const float4v*)(Vg + (size_t)(srow + 16*i) * DD + scol);
    }

    for(int ct = 0; ct < NT; ++ct){
        barrier_lds();                         // A
        #pragma unroll
        for(int i = 0; i < 4; ++i){            // stage K(t) + V^T(t) swizzled
            uint2v t = { cvt_pk_bf16(kreg[i][0], kreg[i][1]),
                         cvt_pk_bf16(kreg[i][2], kreg[i][3]) };
            *(uint2v*)&Kb[srow + 16*i][scol] = t;
            #pragma unroll
            for(int j = 0; j < 4; ++j)
                Vt[scol + j][(srow + 16*i) ^ vsw] = f2bf1(vreg[i][j]);
        }
        float bb[16];
        #pragma unroll
        for(int sub = 0; sub < 4; ++sub)
            #pragma unroll
            for(int r = 0; r < 4; ++r)
                bb[sub*4+r] = BgA[(size_t)r * NN + ct*KT + sub*16];
        if(ct + 1 < NT){                       // prefetch K/V(t+1)
            #pragma unroll
            for(int i = 0; i < 4; ++i){
                kreg[i] = *(const float4v*)(Kg + (size_t)((ct+1)*KT + srow + 16*i) * DD + scol);
                vreg[i] = *(const float4v*)(Vg + (size_t)((ct+1)*KT + srow + 16*i) * DD + scol);
            }
        }
        barrier_lds();                         // B

        float4v acc[4];
        #pragma unroll
        for(int sub = 0; sub < 4; ++sub) acc[sub] = (float4v){0.f,0.f,0.f,0.f};
        __builtin_amdgcn_s_setprio(1);
        #pragma unroll
        for(int sub = 0; sub < 4; ++sub){
            short8 b0 = *(const short8*)&Kb[sub*16 + ll][lg*8];
            short8 b1 = *(const short8*)&Kb[sub*16 + ll][32 + lg*8];
            acc[sub] = mfma_bf16(qf[0], b0, acc[sub]);
            acc[sub] = mfma_bf16(qf[1], b1, acc[sub]);
        }
        __builtin_amdgcn_s_setprio(0);

        // p = exp(s)*rl -> bf16 -> Pbh (acc layout, b16 stores)
        #pragma unroll
        for(int sub = 0; sub < 4; ++sub)
            #pragma unroll
            for(int r = 0; r < 4; ++r){
                float p = __expf(acc[sub][r] * 0.125f + bb[sub*4+r]) * rl[r];
                ((unsigned short*)&Pbh[w][lg*4 + r][0])[sub*16 + ll] = f2bf1(p);
            }

        // wave-internal RAW on Pbh
        asm volatile("s_waitcnt lgkmcnt(0)" ::: "memory");

        // PV A-frags: direct bf16 b128 reads (no cvt)
        short8 pf0 = __builtin_bit_cast(short8, *(const uint4v*)&Pbh[w][ll][lg*4]);
        short8 pf1 = __builtin_bit_cast(short8, *(const uint4v*)&Pbh[w][ll][16 + lg*4]);

        // attn store: vec-layout b64 reads -> fp32 -> dwordx4 stores
        #pragma unroll
        for(int it = 0; it < 4; ++it){
            uint2v pw = *(const uint2v*)&Pbh[w][lg + 4*it][ll*2];
            float4v pv;
            pv[0] = __builtin_bit_cast(float, pw[0] << 16);
            pv[1] = __builtin_bit_cast(float, pw[0] & 0xffff0000u);
            pv[2] = __builtin_bit_cast(float, pw[1] << 16);
            pv[3] = __builtin_bit_cast(float, pw[1] & 0xffff0000u);
            *(float4v*)(attnW + (size_t)(it*4) * NN + ct*KT) = pv;
        }

        // PV MFMA: B-frags from swizzled Vt
        __builtin_amdgcn_s_setprio(1);
        #pragma unroll
        for(int ds = 0; ds < 4; ++ds){
            const int rsw = (2*ds + (ll >> 3)) << 3;
            short8 v0 = *(const short8*)&Vt[ds*16 + ll][(lg*8) ^ rsw];
            short8 v1 = *(const short8*)&Vt[ds*16 + ll][(32 + lg*8) ^ rsw];
            oacc[ds] = mfma_bf16(pf0, v0, oacc[ds]);
            oacc[ds] = mfma_bf16(pf1, v1, oacc[ds]);
        }
        __builtin_amdgcn_s_setprio(0);
    }

    // O store
    float* outG = Out + (bh * NN + qw) * (size_t)DD;
    #pragma unroll
    for(int ds = 0; ds < 4; ++ds)
        #pragma unroll
        for(int r = 0; r < 4; ++r)
            outG[(size_t)(lg*4 + r) * DD + ds*16 + ll] = oacc[ds][r];
}

extern "C" void kernel_launch(void* const* d_in, const int* in_sizes, int n_in,
                              void* d_out, int out_size, void* d_ws, size_t ws_size,
                              hipStream_t stream) {
    const float* q    = (const float*)d_in[0];
    const float* k    = (const float*)d_in[1];
    const float* v    = (const float*)d_in[2];
    const float* bias = (const float*)d_in[3];
    float* out = (float*)d_out;

    dim3 grid(BN * HN * (NN / 64));
    dim3 block(256);
    hipLaunchKernelGGL(attn_fused_kernel, grid, block, 0, stream, q, k, v, bias, out);
}